// Round 11
// baseline (434.536 us; speedup 1.0000x reference)
//
#include <hip/hip_runtime.h>

// HypergraphModel on MI355X.
// R11: fuse each node-side aggregation with its consumer via LDS staging
//      (a3 never hits global: 3x (25.6 MB write + 25.6 MB read) removed,
//      4 launches removed). Phase 1 = gather (unchanged); rows -> LDS
//      (stride 72/40 words: bank-spread, 16B-aligned); phase 2 = row GEMM
//      from LDS (broadcast reads). Decode = 1 thread/row from LDS (no
//      shuffles — R9 lesson). k_bucket+k_compose+k_cast_x merged (k_front).
//      CSR counting sort, bf16 gathers, composed-mu elimination unchanged.

#define NN 100000
#define NE 100000
#define NP 1600000
#define NBK  391   // buckets per side (256 ids each); NBK*256 = 100,096
#define BCAP 4608  // bucket cap (mean 4096, +8 sigma)
#define CCAP 48    // padded CSR row stride (Poisson(16) + >8 sigma)

// ws offsets in 4-byte words (sizes in words) — non-overlapping:
#define O_GCURE 0              // 512  (zeroed)
#define O_GCURN 512            // 512  (zeroed)
#define O_NORM  1024           // 64   (zeroed)
#define O_DEGE  1088           // 100,000
#define O_DEGN  101088         // 100,000
#define O_BINV  201088         // 100,000
#define O_DINV  301088         // 100,000
#define O_BKTE  401088         // NBK*BCAP = 1,801,728
#define O_BKTN  2202816        // 1,801,728
#define O_CSRE  4004544        // NE*CCAP = 4,800,000
#define O_CSRN  8804544        // 4,800,000
#define O_XB    13604544       // bf16 100000x32 = 1,600,000 words
#define O_T     15204544       // bf16 100000x64 = 3,200,000 words
#define O_HE    18404544       // bf16 100000x64 = 3,200,000 words
#define O_C1    21604544       // fp32 64x32 = 2,048 (composed Wmu@dW1)
#define O_C1B   21606592       // fp32 32 (composed bias)
// end 21,606,624 words = 86.4 MB

typedef unsigned int uint32;

__device__ __forceinline__ float b2f_lo(uint32 u) { return __uint_as_float(u << 16); }
__device__ __forceinline__ float b2f_hi(uint32 u) { return __uint_as_float(u & 0xFFFF0000u); }
__device__ __forceinline__ uint32 f2b(float f) {  // RNE fp32 -> bf16
  uint32 b = __float_as_uint(f);
  return (b + 0x7FFFu + ((b >> 16) & 1u)) >> 16;
}
__device__ __forceinline__ uint32 pack2(float lo, float hi) {
  return f2b(lo) | (f2b(hi) << 16);
}

// 8-elem gather-accumulate over a padded-CSR segment (bf16 rows, ROWU uints
// per row, 16B per lane). a[0..7] must be zeroed by caller.
template <int ROWU>
__device__ __forceinline__ void gather8(const uint32* __restrict__ base,
                                        const int* __restrict__ csr,
                                        int beg, int end, float* a) {
#define ACC(q)                                        \
  a[0] += b2f_lo(q.x); a[1] += b2f_hi(q.x);           \
  a[2] += b2f_lo(q.y); a[3] += b2f_hi(q.y);           \
  a[4] += b2f_lo(q.z); a[5] += b2f_hi(q.z);           \
  a[6] += b2f_lo(q.w); a[7] += b2f_hi(q.w);
  int p = beg;
  for (; p + 8 <= end; p += 8) {
    int4 i4a = *(const int4*)(csr + p);
    int4 i4b = *(const int4*)(csr + p + 4);
    uint4 q0 = *(const uint4*)(base + (long)i4a.x * ROWU);
    uint4 q1 = *(const uint4*)(base + (long)i4a.y * ROWU);
    uint4 q2 = *(const uint4*)(base + (long)i4a.z * ROWU);
    uint4 q3 = *(const uint4*)(base + (long)i4a.w * ROWU);
    uint4 q4 = *(const uint4*)(base + (long)i4b.x * ROWU);
    uint4 q5 = *(const uint4*)(base + (long)i4b.y * ROWU);
    uint4 q6 = *(const uint4*)(base + (long)i4b.z * ROWU);
    uint4 q7 = *(const uint4*)(base + (long)i4b.w * ROWU);
    ACC(q0) ACC(q1) ACC(q2) ACC(q3) ACC(q4) ACC(q5) ACC(q6) ACC(q7)
  }
  for (; p + 4 <= end; p += 4) {
    int4 i4 = *(const int4*)(csr + p);
    uint4 q0 = *(const uint4*)(base + (long)i4.x * ROWU);
    uint4 q1 = *(const uint4*)(base + (long)i4.y * ROWU);
    uint4 q2 = *(const uint4*)(base + (long)i4.z * ROWU);
    uint4 q3 = *(const uint4*)(base + (long)i4.w * ROWU);
    ACC(q0) ACC(q1) ACC(q2) ACC(q3)
  }
  for (; p < end; ++p) {
    uint4 q = *(const uint4*)(base + (long)csr[p] * ROWU);
    ACC(q)
  }
#undef ACC
}

// ---- k_front: bucketize (blocks 0..NBK-1) + compose (block NBK) +
//      cast x->bf16 (blocks NBK+1 ..). All independent.
#define CASTB ((NN * 32 / 8 + 255) / 256)  // 1563
__global__ __launch_bounds__(256) void k_front(const int* __restrict__ nidx,
                                               const int* __restrict__ eidx,
                                               int* __restrict__ gcurE,
                                               int* __restrict__ gcurN,
                                               int* __restrict__ bktE,
                                               int* __restrict__ bktN,
                                               const float* __restrict__ Wmu,
                                               const float* __restrict__ bmu,
                                               const float* __restrict__ dW1,
                                               const float* __restrict__ db1,
                                               float* __restrict__ C1,
                                               float* __restrict__ c1,
                                               const float* __restrict__ x,
                                               uint32* __restrict__ xb) {
  __shared__ int cntE[NBK], cntN[NBK], curE[NBK], curN[NBK];
  if (blockIdx.x < NBK) {
    for (int i = threadIdx.x; i < NBK; i += 256) { cntE[i] = 0; cntN[i] = 0; }
    __syncthreads();
    int base = blockIdx.x * 4096 + threadIdx.x * 16;
    int n[16], e[16];
    int cnt = 0;
    if (base + 16 <= NP) {
#pragma unroll
      for (int q = 0; q < 4; ++q) {
        int4 a = *(const int4*)(nidx + base + 4 * q);
        int4 b = *(const int4*)(eidx + base + 4 * q);
        n[4 * q + 0] = a.x; n[4 * q + 1] = a.y; n[4 * q + 2] = a.z; n[4 * q + 3] = a.w;
        e[4 * q + 0] = b.x; e[4 * q + 1] = b.y; e[4 * q + 2] = b.z; e[4 * q + 3] = b.w;
      }
      cnt = 16;
    } else {
      for (int i = 0; i < 16 && base + i < NP; ++i) {
        n[i] = nidx[base + i];
        e[i] = eidx[base + i];
        ++cnt;
      }
    }
    for (int i = 0; i < cnt; ++i) {
      atomicAdd(&cntE[e[i] >> 8], 1);
      atomicAdd(&cntN[n[i] >> 8], 1);
    }
    __syncthreads();
    for (int i = threadIdx.x; i < NBK; i += 256) {
      curE[i] = atomicAdd(&gcurE[i], cntE[i]);
      curN[i] = atomicAdd(&gcurN[i], cntN[i]);
    }
    __syncthreads();
    for (int i = 0; i < cnt; ++i) {
      int be = e[i] >> 8, bn = n[i] >> 8;
      int se = atomicAdd(&curE[be], 1);
      if (se < BCAP) bktE[be * BCAP + se] = ((e[i] & 255) << 24) | n[i];
      int sn = atomicAdd(&curN[bn], 1);
      if (sn < BCAP) bktN[bn * BCAP + sn] = ((n[i] & 255) << 24) | e[i];
    }
  } else if (blockIdx.x == NBK) {
    int t = threadIdx.x;
    for (int idx = t; idx < 64 * 32; idx += 256) {
      int i = idx >> 5, j = idx & 31;
      float s = 0.f;
      for (int k = 0; k < 64; ++k) s += Wmu[i * 64 + k] * dW1[k * 32 + j];
      C1[idx] = s;
    }
    if (t < 32) {
      float s = db1[t];
      for (int k = 0; k < 64; ++k) s += bmu[k] * dW1[k * 32 + t];
      c1[t] = s;
    }
  } else {
    int t = (blockIdx.x - NBK - 1) * 256 + threadIdx.x;
    if (t < NN * 32 / 8) {
      const float4 f0 = *(const float4*)(x + (long)t * 8);
      const float4 f1 = *(const float4*)(x + (long)t * 8 + 4);
      uint4 o;
      o.x = pack2(f0.x, f0.y);
      o.y = pack2(f0.z, f0.w);
      o.z = pack2(f1.x, f1.y);
      o.w = pack2(f1.z, f1.w);
      *(uint4*)(xb + (long)t * 4) = o;
    }
  }
}

// ---- Pass B: per-bucket padded-CSR build + deg + 1/deg (LDS atomics only).
__global__ __launch_bounds__(256) void k_csr2(const int* __restrict__ gcurE,
                                              const int* __restrict__ gcurN,
                                              const int* __restrict__ bktE,
                                              const int* __restrict__ bktN,
                                              int* __restrict__ csrE,
                                              int* __restrict__ csrN,
                                              int* __restrict__ degE,
                                              int* __restrict__ degN,
                                              float* __restrict__ invE,
                                              float* __restrict__ invN) {
  int bb = blockIdx.x;
  bool es = bb < NBK;
  int b = es ? bb : bb - NBK;
  const int* gcur = es ? gcurE : gcurN;
  const int* bkt  = es ? bktE : bktN;
  int*   csr = es ? csrE : csrN;
  int*   deg = es ? degE : degN;
  float* inv = es ? invE : invN;

  __shared__ int ent[BCAP];
  __shared__ int cnt[256], cur[256];
  int m = gcur[b];
  if (m > BCAP) m = BCAP;
  for (int i = threadIdx.x; i < m; i += 256) ent[i] = bkt[b * BCAP + i];
  cnt[threadIdx.x] = 0;
  __syncthreads();
  for (int i = threadIdx.x; i < m; i += 256)
    atomicAdd(&cnt[((unsigned)ent[i]) >> 24], 1);
  __syncthreads();
  int id = (b << 8) + threadIdx.x;
  if (id < NN) {  // NN == NE
    int d = cnt[threadIdx.x];
    deg[id] = d < CCAP ? d : CCAP;
    inv[id] = d > 0 ? 1.0f / (float)d : 0.0f;
  }
  cur[threadIdx.x] = 0;
  __syncthreads();
  for (int i = threadIdx.x; i < m; i += 256) {
    unsigned v = (unsigned)ent[i];
    int loc = v >> 24;
    int payload = v & 0xFFFFFF;
    int slot = atomicAdd(&cur[loc], 1);
    if (slot < CCAP) csr[(long)((b << 8) + loc) * CCAP + slot] = payload;
  }
}

// Edge-side gather-reduce, bf16 in / bf16 out (unchanged from R10).
template <int W>
__global__ __launch_bounds__(256) void k_seg_agg(const uint32* __restrict__ tb,
                                                 const int* __restrict__ csr,
                                                 const int* __restrict__ deg,
                                                 const float* __restrict__ inv,
                                                 uint32* __restrict__ dstb) {
  constexpr int LANES = W / 8;
  constexpr int ROWU = W / 2;
  int g = blockIdx.x * 256 + threadIdx.x;
  int s = g / LANES;
  int lane = g % LANES;
  if (s >= NE) return;
  int d = deg[s];
  float a[8] = {0.f, 0.f, 0.f, 0.f, 0.f, 0.f, 0.f, 0.f};
  gather8<ROWU>(tb + (long)lane * 4, csr, s * CCAP, s * CCAP + d, a);
  float sc = inv[s];
  uint4 o;
  o.x = pack2(a[0] * sc, a[1] * sc);
  o.y = pack2(a[2] * sc, a[3] * sc);
  o.z = pack2(a[4] * sc, a[5] * sc);
  o.w = pack2(a[6] * sc, a[7] * sc);
  *(uint4*)(dstb + (long)s * ROWU + lane * 4) = o;
}

// ---- Fused node-agg (32-wide) + GEMM(32->64) + LN + leaky -> bf16 t.
// 64 segments/block (4 lanes each); rows staged in LDS (stride 40 words).
#define R32 40
__global__ __launch_bounds__(256) void k_agg_ln(
    const uint32* __restrict__ he, const int* __restrict__ csr,
    const int* __restrict__ deg, const float* __restrict__ inv,
    const float* __restrict__ W1, const float* __restrict__ b1,
    const float* __restrict__ g1, const float* __restrict__ be1,
    uint32* __restrict__ h) {
  __shared__ float Ws[32 * 64];
  __shared__ __align__(16) float rows[64 * R32];
  for (int i = threadIdx.x; i < 32 * 64; i += 256) Ws[i] = W1[i];
  int sl = threadIdx.x >> 2;
  int lane = threadIdx.x & 3;
  int s = blockIdx.x * 64 + sl;
  if (s < NN) {
    int d = deg[s];
    float a[8] = {0.f, 0.f, 0.f, 0.f, 0.f, 0.f, 0.f, 0.f};
    gather8<16>(he + (long)lane * 4, csr, s * CCAP, s * CCAP + d, a);
    float sc = inv[s];
    float4 o0 = {a[0] * sc, a[1] * sc, a[2] * sc, a[3] * sc};
    float4 o1 = {a[4] * sc, a[5] * sc, a[6] * sc, a[7] * sc};
    *(float4*)(&rows[sl * R32 + lane * 8]) = o0;
    *(float4*)(&rows[sl * R32 + lane * 8 + 4]) = o1;
  }
  __syncthreads();
#pragma unroll
  for (int pass = 0; pass < 4; ++pass) {
    int rl = pass * 16 + (threadIdx.x >> 4);
    int r = blockIdx.x * 64 + rl;
    int l = (threadIdx.x & 15) * 4;
    float vx = b1[l + 0], vy = b1[l + 1], vz = b1[l + 2], vw = b1[l + 3];
    const float* row = &rows[rl * R32];
#pragma unroll
    for (int kk = 0; kk < 8; ++kk) {
      float4 rv = *(const float4*)(row + 4 * kk);
      const float* w0 = &Ws[(4 * kk + 0) * 64 + l];
      const float* w1 = &Ws[(4 * kk + 1) * 64 + l];
      const float* w2 = &Ws[(4 * kk + 2) * 64 + l];
      const float* w3 = &Ws[(4 * kk + 3) * 64 + l];
      vx += rv.x * w0[0] + rv.y * w1[0] + rv.z * w2[0] + rv.w * w3[0];
      vy += rv.x * w0[1] + rv.y * w1[1] + rv.z * w2[1] + rv.w * w3[1];
      vz += rv.x * w0[2] + rv.y * w1[2] + rv.z * w2[2] + rv.w * w3[2];
      vw += rv.x * w0[3] + rv.y * w1[3] + rv.z * w2[3] + rv.w * w3[3];
    }
    float sm = vx + vy + vz + vw;
    float s2 = vx * vx + vy * vy + vz * vz + vw * vw;
    for (int m = 1; m <= 8; m <<= 1) {
      sm += __shfl_xor(sm, m, 64);
      s2 += __shfl_xor(s2, m, 64);
    }
    float mean = sm * (1.0f / 64.0f);
    float var = s2 * (1.0f / 64.0f) - mean * mean;
    float rstd = rsqrtf(var + 1e-5f);
    if (r < NN) {
      float ox = (vx - mean) * rstd * g1[l + 0] + be1[l + 0];
      float oy = (vy - mean) * rstd * g1[l + 1] + be1[l + 1];
      float oz = (vz - mean) * rstd * g1[l + 2] + be1[l + 2];
      float ow = (vw - mean) * rstd * g1[l + 3] + be1[l + 3];
      ox = ox >= 0.f ? ox : 0.01f * ox;
      oy = oy >= 0.f ? oy : 0.01f * oy;
      oz = oz >= 0.f ? oz : 0.01f * oz;
      ow = ow >= 0.f ? ow : 0.01f * ow;
      uint2 o = {pack2(ox, oy), pack2(oz, ow)};
      *(uint2*)(h + (long)r * 32 + (l >> 1)) = o;
    }
  }
}

// ---- Fused node-agg (64-wide) + GEMM(64->64) + leaky -> bf16 t.
// 32 segments/block (8 lanes each); LDS rows stride 72 words.
#define R64 72
__global__ __launch_bounds__(256) void k_agg_lk(
    const uint32* __restrict__ he, const int* __restrict__ csr,
    const int* __restrict__ deg, const float* __restrict__ inv,
    const float* __restrict__ W2, const float* __restrict__ b2,
    uint32* __restrict__ h2) {
  __shared__ float Ws[64 * 64];
  __shared__ __align__(16) float rows[32 * R64];
  for (int i = threadIdx.x; i < 64 * 64; i += 256) Ws[i] = W2[i];
  int sl = threadIdx.x >> 3;
  int lane = threadIdx.x & 7;
  int s = blockIdx.x * 32 + sl;
  if (s < NN) {
    int d = deg[s];
    float a[8] = {0.f, 0.f, 0.f, 0.f, 0.f, 0.f, 0.f, 0.f};
    gather8<32>(he + (long)lane * 4, csr, s * CCAP, s * CCAP + d, a);
    float sc = inv[s];
    float4 o0 = {a[0] * sc, a[1] * sc, a[2] * sc, a[3] * sc};
    float4 o1 = {a[4] * sc, a[5] * sc, a[6] * sc, a[7] * sc};
    *(float4*)(&rows[sl * R64 + lane * 8]) = o0;
    *(float4*)(&rows[sl * R64 + lane * 8 + 4]) = o1;
  }
  __syncthreads();
#pragma unroll
  for (int pass = 0; pass < 2; ++pass) {
    int rl = pass * 16 + (threadIdx.x >> 4);
    int r = blockIdx.x * 32 + rl;
    int l = (threadIdx.x & 15) * 4;
    float vx = b2[l + 0], vy = b2[l + 1], vz = b2[l + 2], vw = b2[l + 3];
    const float* row = &rows[rl * R64];
#pragma unroll
    for (int kk = 0; kk < 16; ++kk) {
      float4 rv = *(const float4*)(row + 4 * kk);
      const float* w0 = &Ws[(4 * kk + 0) * 64 + l];
      const float* w1 = &Ws[(4 * kk + 1) * 64 + l];
      const float* w2 = &Ws[(4 * kk + 2) * 64 + l];
      const float* w3 = &Ws[(4 * kk + 3) * 64 + l];
      vx += rv.x * w0[0] + rv.y * w1[0] + rv.z * w2[0] + rv.w * w3[0];
      vy += rv.x * w0[1] + rv.y * w1[1] + rv.z * w2[1] + rv.w * w3[1];
      vz += rv.x * w0[2] + rv.y * w1[2] + rv.z * w2[2] + rv.w * w3[2];
      vw += rv.x * w0[3] + rv.y * w1[3] + rv.z * w2[3] + rv.w * w3[3];
    }
    if (r < NN) {
      vx = vx >= 0.f ? vx : 0.01f * vx;
      vy = vy >= 0.f ? vy : 0.01f * vy;
      vz = vz >= 0.f ? vz : 0.01f * vz;
      vw = vw >= 0.f ? vw : 0.01f * vw;
      uint2 o = {pack2(vx, vy), pack2(vz, vw)};
      *(uint2*)(h2 + (long)r * 32 + (l >> 1)) = o;
    }
  }
}

// ---- Fused node-agg (64-wide) + logvar GEMM + composed decode + norm.
__global__ __launch_bounds__(256) void k_agg_heads(
    const uint32* __restrict__ he, const int* __restrict__ csr,
    const int* __restrict__ deg, const float* __restrict__ inv,
    const float* __restrict__ Wlv, const float* __restrict__ blv,
    const float* __restrict__ C1, const float* __restrict__ c1,
    const float* __restrict__ dW2, const float* __restrict__ db2,
    const float* __restrict__ dW3, const float* __restrict__ db3,
    float* __restrict__ out, float* __restrict__ lv,
    float* __restrict__ norm_acc) {
  __shared__ float Ws[64 * 64];
  __shared__ float C1s[64 * 32];
  __shared__ float W2s[32 * 8];
  __shared__ float W3s[8];
  __shared__ float c1s[32];
  __shared__ float b2s[8];
  __shared__ float b3s;
  __shared__ float red2[32];
  __shared__ __align__(16) float rows[32 * R64];
  for (int i = threadIdx.x; i < 64 * 64; i += 256) Ws[i] = Wlv[i];
  for (int i = threadIdx.x; i < 64 * 32; i += 256) C1s[i] = C1[i];
  if (threadIdx.x < 256) W2s[threadIdx.x] = dW2[threadIdx.x];
  if (threadIdx.x < 32) c1s[threadIdx.x] = c1[threadIdx.x];
  if (threadIdx.x < 8) {
    W3s[threadIdx.x] = dW3[threadIdx.x];
    b2s[threadIdx.x] = db2[threadIdx.x];
  }
  if (threadIdx.x == 0) b3s = db3[0];
  int sl = threadIdx.x >> 3;
  int lane = threadIdx.x & 7;
  int s = blockIdx.x * 32 + sl;
  if (s < NN) {
    int d = deg[s];
    float a[8] = {0.f, 0.f, 0.f, 0.f, 0.f, 0.f, 0.f, 0.f};
    gather8<32>(he + (long)lane * 4, csr, s * CCAP, s * CCAP + d, a);
    float sc = inv[s];
    float4 o0 = {a[0] * sc, a[1] * sc, a[2] * sc, a[3] * sc};
    float4 o1 = {a[4] * sc, a[5] * sc, a[6] * sc, a[7] * sc};
    *(float4*)(&rows[sl * R64 + lane * 8]) = o0;
    *(float4*)(&rows[sl * R64 + lane * 8 + 4]) = o1;
  }
  __syncthreads();
  // phase 2a: logvar GEMM (16 lanes/row, 2 passes)
#pragma unroll
  for (int pass = 0; pass < 2; ++pass) {
    int rl = pass * 16 + (threadIdx.x >> 4);
    int r = blockIdx.x * 32 + rl;
    int l = (threadIdx.x & 15) * 4;
    float vx = blv[l + 0], vy = blv[l + 1], vz = blv[l + 2], vw = blv[l + 3];
    const float* row = &rows[rl * R64];
#pragma unroll
    for (int kk = 0; kk < 16; ++kk) {
      float4 rv = *(const float4*)(row + 4 * kk);
      const float* w0 = &Ws[(4 * kk + 0) * 64 + l];
      const float* w1 = &Ws[(4 * kk + 1) * 64 + l];
      const float* w2 = &Ws[(4 * kk + 2) * 64 + l];
      const float* w3 = &Ws[(4 * kk + 3) * 64 + l];
      vx += rv.x * w0[0] + rv.y * w1[0] + rv.z * w2[0] + rv.w * w3[0];
      vy += rv.x * w0[1] + rv.y * w1[1] + rv.z * w2[1] + rv.w * w3[1];
      vz += rv.x * w0[2] + rv.y * w1[2] + rv.z * w2[2] + rv.w * w3[2];
      vw += rv.x * w0[3] + rv.y * w1[3] + rv.z * w2[3] + rv.w * w3[3];
    }
    if (r < NN) {
      float4 o = {vx, vy, vz, vw};
      *(float4*)(&lv[(long)r * 64 + l]) = o;
    }
  }
  // phase 2b: composed decode, one thread per row (no cross-lane)
  float dval = 0.f;
  if (threadIdx.x < 32) {
    int r = blockIdx.x * 32 + threadIdx.x;
    if (r < NN) {
      const float* row = &rows[threadIdx.x * R64];
      float acc[32];
#pragma unroll
      for (int j = 0; j < 32; ++j) acc[j] = c1s[j];
      for (int kk = 0; kk < 16; ++kk) {
        float4 rv = *(const float4*)(row + 4 * kk);
        const float* r0 = &C1s[(4 * kk + 0) * 32];
        const float* r1 = &C1s[(4 * kk + 1) * 32];
        const float* r2 = &C1s[(4 * kk + 2) * 32];
        const float* r3 = &C1s[(4 * kk + 3) * 32];
#pragma unroll
        for (int j = 0; j < 32; ++j)
          acc[j] += rv.x * r0[j] + rv.y * r1[j] + rv.z * r2[j] + rv.w * r3[j];
      }
      float a2[8];
#pragma unroll
      for (int j = 0; j < 8; ++j) a2[j] = b2s[j];
#pragma unroll
      for (int k = 0; k < 32; ++k) {
        float v = acc[k];
        v = v >= 0.f ? v : 0.01f * v;
#pragma unroll
        for (int j = 0; j < 8; ++j) a2[j] += v * W2s[k * 8 + j];
      }
      float sfin = b3s;
#pragma unroll
      for (int k = 0; k < 8; ++k) {
        float v = a2[k];
        v = v >= 0.f ? v : 0.01f * v;
        sfin += v * W3s[k];
      }
      dval = sfin;
      out[r] = dval;        // z_orth (unscaled)
      out[NN + r] = dval;   // mu_orth (z == mu in eval mode)
    }
    red2[threadIdx.x] = dval * dval;
  }
  __syncthreads();
  if (threadIdx.x == 0) {
    float t = 0.f;
#pragma unroll
    for (int k = 0; k < 32; ++k) t += red2[k];
    atomicAdd(norm_acc, t);
  }
}

__global__ __launch_bounds__(256) void k_scale(float* __restrict__ out,
                                               const float* __restrict__ norm_acc) {
  int i = blockIdx.x * 256 + threadIdx.x;
  if (i < 2 * NN) {
    float nrm = sqrtf(*norm_acc);
    float sc = 1.0f / fmaxf(nrm, 1e-8f);
    out[i] *= sc;
  }
}

extern "C" void kernel_launch(void* const* d_in, const int* in_sizes, int n_in,
                              void* d_out, int out_size, void* d_ws, size_t ws_size,
                              hipStream_t stream) {
  const float* x   = (const float*)d_in[0];
  const int*   hei = (const int*)d_in[1];  // [2, NP]
  const int* nidx = hei;
  const int* eidx = hei + NP;
  const float* W1  = (const float*)d_in[2];
  const float* b1  = (const float*)d_in[3];
  const float* g1  = (const float*)d_in[4];
  const float* be1 = (const float*)d_in[5];
  const float* W2  = (const float*)d_in[6];
  const float* b2  = (const float*)d_in[7];
  const float* Wmu = (const float*)d_in[8];
  const float* bmu = (const float*)d_in[9];
  const float* Wlv = (const float*)d_in[10];
  const float* blv = (const float*)d_in[11];
  const float* dW1 = (const float*)d_in[12];
  const float* db1 = (const float*)d_in[13];
  const float* dW2 = (const float*)d_in[14];
  const float* db2 = (const float*)d_in[15];
  const float* dW3 = (const float*)d_in[16];
  const float* db3 = (const float*)d_in[17];
  float* out = (float*)d_out;

  int*    wi = (int*)d_ws;
  float*  wf = (float*)d_ws;
  uint32* wu = (uint32*)d_ws;

  // zero gcurE/gcurN/norm (words 0 .. 1087)
  hipMemsetAsync(d_ws, 0, (size_t)1088 * 4, stream);

  // front: bucketize + compose + cast in one launch
  k_front<<<NBK + 1 + CASTB, 256, 0, stream>>>(nidx, eidx,
                                               wi + O_GCURE, wi + O_GCURN,
                                               wi + O_BKTE, wi + O_BKTN,
                                               Wmu, bmu, dW1, db1,
                                               wf + O_C1, wf + O_C1B,
                                               x, wu + O_XB);
  k_csr2<<<2 * NBK, 256, 0, stream>>>(wi + O_GCURE, wi + O_GCURN,
                                      wi + O_BKTE, wi + O_BKTN,
                                      wi + O_CSRE, wi + O_CSRN,
                                      wi + O_DEGE, wi + O_DEGN,
                                      wf + O_BINV, wf + O_DINV);

  const int G32 = (NE * 4 + 255) / 256;   // edge agg 32-wide
  const int G64 = (NE * 8 + 255) / 256;   // edge agg 64-wide

  // layer 1
  k_seg_agg<32><<<G32, 256, 0, stream>>>(wu + O_XB, wi + O_CSRE,
                                         wi + O_DEGE, wf + O_BINV, wu + O_HE);
  k_agg_ln<<<(NN + 63) / 64, 256, 0, stream>>>(wu + O_HE, wi + O_CSRN,
                                               wi + O_DEGN, wf + O_DINV,
                                               W1, b1, g1, be1, wu + O_T);
  // layer 2
  k_seg_agg<64><<<G64, 256, 0, stream>>>(wu + O_T, wi + O_CSRE,
                                         wi + O_DEGE, wf + O_BINV, wu + O_HE);
  k_agg_lk<<<(NN + 31) / 32, 256, 0, stream>>>(wu + O_HE, wi + O_CSRN,
                                               wi + O_DEGN, wf + O_DINV,
                                               W2, b2, wu + O_T);
  // heads
  k_seg_agg<64><<<G64, 256, 0, stream>>>(wu + O_T, wi + O_CSRE,
                                         wi + O_DEGE, wf + O_BINV, wu + O_HE);
  k_agg_heads<<<(NN + 31) / 32, 256, 0, stream>>>(wu + O_HE, wi + O_CSRN,
                                                  wi + O_DEGN, wf + O_DINV,
                                                  Wlv, blv, wf + O_C1, wf + O_C1B,
                                                  dW2, db2, dW3, db3,
                                                  out, out + 2 * NN, wf + O_NORM);
  k_scale<<<(2 * NN + 255) / 256, 256, 0, stream>>>(out, wf + O_NORM);
}

// Round 12
// 404.690 us; speedup vs baseline: 1.0738x; 1.0738x over previous
//
#include <hip/hip_runtime.h>

// HypergraphModel on MI355X.
// R12: hybrid of R10/R11. Keep R11's fused k_agg_ln / k_agg_lk (thin
//      consumers, all threads busy in phase 2). REVERT the heads fusion:
//      R11's k_agg_heads measured 116 us vs ~83 for the split path (26%
//      occupancy gather + 800-MAC serial tail on 32/256 threads). Heads =
//      R10's proven k_seg_agg(OUT_F32) -> a3 -> k_gemm_lv + k_decode.

#define NN 100000
#define NE 100000
#define NP 1600000
#define NBK  391   // buckets per side (256 ids each); NBK*256 = 100,096
#define BCAP 4608  // bucket cap (mean 4096, +8 sigma)
#define CCAP 48    // padded CSR row stride (Poisson(16) + >8 sigma)

// ws offsets in 4-byte words (sizes in words) — non-overlapping:
#define O_GCURE 0              // 512  (zeroed)
#define O_GCURN 512            // 512  (zeroed)
#define O_NORM  1024           // 64   (zeroed)
#define O_DEGE  1088           // 100,000
#define O_DEGN  101088         // 100,000
#define O_BINV  201088         // 100,000
#define O_DINV  301088         // 100,000
#define O_BKTE  401088         // NBK*BCAP = 1,801,728
#define O_BKTN  2202816        // 1,801,728
#define O_CSRE  4004544        // NE*CCAP = 4,800,000
#define O_CSRN  8804544        // 4,800,000
#define O_XB    13604544       // bf16 100000x32 = 1,600,000 words
#define O_T     15204544       // bf16 100000x64 = 3,200,000 words
#define O_HE    18404544       // bf16 100000x64 = 3,200,000 words
#define O_C1    21604544       // fp32 64x32 = 2,048
#define O_C1B   21606592       // fp32 32
#define O_A     21606624       // fp32 100000x64 = 6,400,000 words
// end 28,006,624 words = 112 MB

typedef unsigned int uint32;

__device__ __forceinline__ float b2f_lo(uint32 u) { return __uint_as_float(u << 16); }
__device__ __forceinline__ float b2f_hi(uint32 u) { return __uint_as_float(u & 0xFFFF0000u); }
__device__ __forceinline__ uint32 f2b(float f) {  // RNE fp32 -> bf16
  uint32 b = __float_as_uint(f);
  return (b + 0x7FFFu + ((b >> 16) & 1u)) >> 16;
}
__device__ __forceinline__ uint32 pack2(float lo, float hi) {
  return f2b(lo) | (f2b(hi) << 16);
}

// 8-elem gather-accumulate over a padded-CSR segment (bf16 rows, ROWU uints
// per row, 16B per lane). a[0..7] must be zeroed by caller.
template <int ROWU>
__device__ __forceinline__ void gather8(const uint32* __restrict__ base,
                                        const int* __restrict__ csr,
                                        int beg, int end, float* a) {
#define ACC(q)                                        \
  a[0] += b2f_lo(q.x); a[1] += b2f_hi(q.x);           \
  a[2] += b2f_lo(q.y); a[3] += b2f_hi(q.y);           \
  a[4] += b2f_lo(q.z); a[5] += b2f_hi(q.z);           \
  a[6] += b2f_lo(q.w); a[7] += b2f_hi(q.w);
  int p = beg;
  for (; p + 8 <= end; p += 8) {
    int4 i4a = *(const int4*)(csr + p);
    int4 i4b = *(const int4*)(csr + p + 4);
    uint4 q0 = *(const uint4*)(base + (long)i4a.x * ROWU);
    uint4 q1 = *(const uint4*)(base + (long)i4a.y * ROWU);
    uint4 q2 = *(const uint4*)(base + (long)i4a.z * ROWU);
    uint4 q3 = *(const uint4*)(base + (long)i4a.w * ROWU);
    uint4 q4 = *(const uint4*)(base + (long)i4b.x * ROWU);
    uint4 q5 = *(const uint4*)(base + (long)i4b.y * ROWU);
    uint4 q6 = *(const uint4*)(base + (long)i4b.z * ROWU);
    uint4 q7 = *(const uint4*)(base + (long)i4b.w * ROWU);
    ACC(q0) ACC(q1) ACC(q2) ACC(q3) ACC(q4) ACC(q5) ACC(q6) ACC(q7)
  }
  for (; p + 4 <= end; p += 4) {
    int4 i4 = *(const int4*)(csr + p);
    uint4 q0 = *(const uint4*)(base + (long)i4.x * ROWU);
    uint4 q1 = *(const uint4*)(base + (long)i4.y * ROWU);
    uint4 q2 = *(const uint4*)(base + (long)i4.z * ROWU);
    uint4 q3 = *(const uint4*)(base + (long)i4.w * ROWU);
    ACC(q0) ACC(q1) ACC(q2) ACC(q3)
  }
  for (; p < end; ++p) {
    uint4 q = *(const uint4*)(base + (long)csr[p] * ROWU);
    ACC(q)
  }
#undef ACC
}

// ---- k_front: bucketize (blocks 0..NBK-1) + compose (block NBK) +
//      cast x->bf16 (blocks NBK+1 ..). All independent.
#define CASTB ((NN * 32 / 8 + 255) / 256)  // 1563
__global__ __launch_bounds__(256) void k_front(const int* __restrict__ nidx,
                                               const int* __restrict__ eidx,
                                               int* __restrict__ gcurE,
                                               int* __restrict__ gcurN,
                                               int* __restrict__ bktE,
                                               int* __restrict__ bktN,
                                               const float* __restrict__ Wmu,
                                               const float* __restrict__ bmu,
                                               const float* __restrict__ dW1,
                                               const float* __restrict__ db1,
                                               float* __restrict__ C1,
                                               float* __restrict__ c1,
                                               const float* __restrict__ x,
                                               uint32* __restrict__ xb) {
  __shared__ int cntE[NBK], cntN[NBK], curE[NBK], curN[NBK];
  if (blockIdx.x < NBK) {
    for (int i = threadIdx.x; i < NBK; i += 256) { cntE[i] = 0; cntN[i] = 0; }
    __syncthreads();
    int base = blockIdx.x * 4096 + threadIdx.x * 16;
    int n[16], e[16];
    int cnt = 0;
    if (base + 16 <= NP) {
#pragma unroll
      for (int q = 0; q < 4; ++q) {
        int4 a = *(const int4*)(nidx + base + 4 * q);
        int4 b = *(const int4*)(eidx + base + 4 * q);
        n[4 * q + 0] = a.x; n[4 * q + 1] = a.y; n[4 * q + 2] = a.z; n[4 * q + 3] = a.w;
        e[4 * q + 0] = b.x; e[4 * q + 1] = b.y; e[4 * q + 2] = b.z; e[4 * q + 3] = b.w;
      }
      cnt = 16;
    } else {
      for (int i = 0; i < 16 && base + i < NP; ++i) {
        n[i] = nidx[base + i];
        e[i] = eidx[base + i];
        ++cnt;
      }
    }
    for (int i = 0; i < cnt; ++i) {
      atomicAdd(&cntE[e[i] >> 8], 1);
      atomicAdd(&cntN[n[i] >> 8], 1);
    }
    __syncthreads();
    for (int i = threadIdx.x; i < NBK; i += 256) {
      curE[i] = atomicAdd(&gcurE[i], cntE[i]);
      curN[i] = atomicAdd(&gcurN[i], cntN[i]);
    }
    __syncthreads();
    for (int i = 0; i < cnt; ++i) {
      int be = e[i] >> 8, bn = n[i] >> 8;
      int se = atomicAdd(&curE[be], 1);
      if (se < BCAP) bktE[be * BCAP + se] = ((e[i] & 255) << 24) | n[i];
      int sn = atomicAdd(&curN[bn], 1);
      if (sn < BCAP) bktN[bn * BCAP + sn] = ((n[i] & 255) << 24) | e[i];
    }
  } else if (blockIdx.x == NBK) {
    int t = threadIdx.x;
    for (int idx = t; idx < 64 * 32; idx += 256) {
      int i = idx >> 5, j = idx & 31;
      float s = 0.f;
      for (int k = 0; k < 64; ++k) s += Wmu[i * 64 + k] * dW1[k * 32 + j];
      C1[idx] = s;
    }
    if (t < 32) {
      float s = db1[t];
      for (int k = 0; k < 64; ++k) s += bmu[k] * dW1[k * 32 + t];
      c1[t] = s;
    }
  } else {
    int t = (blockIdx.x - NBK - 1) * 256 + threadIdx.x;
    if (t < NN * 32 / 8) {
      const float4 f0 = *(const float4*)(x + (long)t * 8);
      const float4 f1 = *(const float4*)(x + (long)t * 8 + 4);
      uint4 o;
      o.x = pack2(f0.x, f0.y);
      o.y = pack2(f0.z, f0.w);
      o.z = pack2(f1.x, f1.y);
      o.w = pack2(f1.z, f1.w);
      *(uint4*)(xb + (long)t * 4) = o;
    }
  }
}

// ---- Pass B: per-bucket padded-CSR build + deg + 1/deg (LDS atomics only).
__global__ __launch_bounds__(256) void k_csr2(const int* __restrict__ gcurE,
                                              const int* __restrict__ gcurN,
                                              const int* __restrict__ bktE,
                                              const int* __restrict__ bktN,
                                              int* __restrict__ csrE,
                                              int* __restrict__ csrN,
                                              int* __restrict__ degE,
                                              int* __restrict__ degN,
                                              float* __restrict__ invE,
                                              float* __restrict__ invN) {
  int bb = blockIdx.x;
  bool es = bb < NBK;
  int b = es ? bb : bb - NBK;
  const int* gcur = es ? gcurE : gcurN;
  const int* bkt  = es ? bktE : bktN;
  int*   csr = es ? csrE : csrN;
  int*   deg = es ? degE : degN;
  float* inv = es ? invE : invN;

  __shared__ int ent[BCAP];
  __shared__ int cnt[256], cur[256];
  int m = gcur[b];
  if (m > BCAP) m = BCAP;
  for (int i = threadIdx.x; i < m; i += 256) ent[i] = bkt[b * BCAP + i];
  cnt[threadIdx.x] = 0;
  __syncthreads();
  for (int i = threadIdx.x; i < m; i += 256)
    atomicAdd(&cnt[((unsigned)ent[i]) >> 24], 1);
  __syncthreads();
  int id = (b << 8) + threadIdx.x;
  if (id < NN) {  // NN == NE
    int d = cnt[threadIdx.x];
    deg[id] = d < CCAP ? d : CCAP;
    inv[id] = d > 0 ? 1.0f / (float)d : 0.0f;
  }
  cur[threadIdx.x] = 0;
  __syncthreads();
  for (int i = threadIdx.x; i < m; i += 256) {
    unsigned v = (unsigned)ent[i];
    int loc = v >> 24;
    int payload = v & 0xFFFFFF;
    int slot = atomicAdd(&cur[loc], 1);
    if (slot < CCAP) csr[(long)((b << 8) + loc) * CCAP + slot] = payload;
  }
}

// Gather-reduce, bf16 in / (bf16 | fp32) out.
template <int W, bool OUT_F32>
__global__ __launch_bounds__(256) void k_seg_agg(const uint32* __restrict__ tb,
                                                 const int* __restrict__ csr,
                                                 const int* __restrict__ deg,
                                                 const float* __restrict__ inv,
                                                 uint32* __restrict__ dstb,
                                                 float* __restrict__ dstf) {
  constexpr int LANES = W / 8;
  constexpr int ROWU = W / 2;
  int g = blockIdx.x * 256 + threadIdx.x;
  int s = g / LANES;
  int lane = g % LANES;
  if (s >= NE) return;
  int d = deg[s];
  float a[8] = {0.f, 0.f, 0.f, 0.f, 0.f, 0.f, 0.f, 0.f};
  gather8<ROWU>(tb + (long)lane * 4, csr, s * CCAP, s * CCAP + d, a);
  float sc = inv[s];
  if (OUT_F32) {
    float* dd = dstf + (long)s * W + lane * 8;
    float4 o0 = {a[0] * sc, a[1] * sc, a[2] * sc, a[3] * sc};
    float4 o1 = {a[4] * sc, a[5] * sc, a[6] * sc, a[7] * sc};
    *(float4*)(dd) = o0;
    *(float4*)(dd + 4) = o1;
  } else {
    uint4 o;
    o.x = pack2(a[0] * sc, a[1] * sc);
    o.y = pack2(a[2] * sc, a[3] * sc);
    o.z = pack2(a[4] * sc, a[5] * sc);
    o.w = pack2(a[6] * sc, a[7] * sc);
    *(uint4*)(dstb + (long)s * ROWU + lane * 4) = o;
  }
}

// ---- Fused node-agg (32-wide) + GEMM(32->64) + LN + leaky -> bf16 t.
#define R32 40
__global__ __launch_bounds__(256) void k_agg_ln(
    const uint32* __restrict__ he, const int* __restrict__ csr,
    const int* __restrict__ deg, const float* __restrict__ inv,
    const float* __restrict__ W1, const float* __restrict__ b1,
    const float* __restrict__ g1, const float* __restrict__ be1,
    uint32* __restrict__ h) {
  __shared__ float Ws[32 * 64];
  __shared__ __align__(16) float rows[64 * R32];
  for (int i = threadIdx.x; i < 32 * 64; i += 256) Ws[i] = W1[i];
  int sl = threadIdx.x >> 2;
  int lane = threadIdx.x & 3;
  int s = blockIdx.x * 64 + sl;
  if (s < NN) {
    int d = deg[s];
    float a[8] = {0.f, 0.f, 0.f, 0.f, 0.f, 0.f, 0.f, 0.f};
    gather8<16>(he + (long)lane * 4, csr, s * CCAP, s * CCAP + d, a);
    float sc = inv[s];
    float4 o0 = {a[0] * sc, a[1] * sc, a[2] * sc, a[3] * sc};
    float4 o1 = {a[4] * sc, a[5] * sc, a[6] * sc, a[7] * sc};
    *(float4*)(&rows[sl * R32 + lane * 8]) = o0;
    *(float4*)(&rows[sl * R32 + lane * 8 + 4]) = o1;
  }
  __syncthreads();
#pragma unroll
  for (int pass = 0; pass < 4; ++pass) {
    int rl = pass * 16 + (threadIdx.x >> 4);
    int r = blockIdx.x * 64 + rl;
    int l = (threadIdx.x & 15) * 4;
    float vx = b1[l + 0], vy = b1[l + 1], vz = b1[l + 2], vw = b1[l + 3];
    const float* row = &rows[rl * R32];
#pragma unroll
    for (int kk = 0; kk < 8; ++kk) {
      float4 rv = *(const float4*)(row + 4 * kk);
      const float* w0 = &Ws[(4 * kk + 0) * 64 + l];
      const float* w1 = &Ws[(4 * kk + 1) * 64 + l];
      const float* w2 = &Ws[(4 * kk + 2) * 64 + l];
      const float* w3 = &Ws[(4 * kk + 3) * 64 + l];
      vx += rv.x * w0[0] + rv.y * w1[0] + rv.z * w2[0] + rv.w * w3[0];
      vy += rv.x * w0[1] + rv.y * w1[1] + rv.z * w2[1] + rv.w * w3[1];
      vz += rv.x * w0[2] + rv.y * w1[2] + rv.z * w2[2] + rv.w * w3[2];
      vw += rv.x * w0[3] + rv.y * w1[3] + rv.z * w2[3] + rv.w * w3[3];
    }
    float sm = vx + vy + vz + vw;
    float s2 = vx * vx + vy * vy + vz * vz + vw * vw;
    for (int m = 1; m <= 8; m <<= 1) {
      sm += __shfl_xor(sm, m, 64);
      s2 += __shfl_xor(s2, m, 64);
    }
    float mean = sm * (1.0f / 64.0f);
    float var = s2 * (1.0f / 64.0f) - mean * mean;
    float rstd = rsqrtf(var + 1e-5f);
    if (r < NN) {
      float ox = (vx - mean) * rstd * g1[l + 0] + be1[l + 0];
      float oy = (vy - mean) * rstd * g1[l + 1] + be1[l + 1];
      float oz = (vz - mean) * rstd * g1[l + 2] + be1[l + 2];
      float ow = (vw - mean) * rstd * g1[l + 3] + be1[l + 3];
      ox = ox >= 0.f ? ox : 0.01f * ox;
      oy = oy >= 0.f ? oy : 0.01f * oy;
      oz = oz >= 0.f ? oz : 0.01f * oz;
      ow = ow >= 0.f ? ow : 0.01f * ow;
      uint2 o = {pack2(ox, oy), pack2(oz, ow)};
      *(uint2*)(h + (long)r * 32 + (l >> 1)) = o;
    }
  }
}

// ---- Fused node-agg (64-wide) + GEMM(64->64) + leaky -> bf16 t.
#define R64 72
__global__ __launch_bounds__(256) void k_agg_lk(
    const uint32* __restrict__ he, const int* __restrict__ csr,
    const int* __restrict__ deg, const float* __restrict__ inv,
    const float* __restrict__ W2, const float* __restrict__ b2,
    uint32* __restrict__ h2) {
  __shared__ float Ws[64 * 64];
  __shared__ __align__(16) float rows[32 * R64];
  for (int i = threadIdx.x; i < 64 * 64; i += 256) Ws[i] = W2[i];
  int sl = threadIdx.x >> 3;
  int lane = threadIdx.x & 7;
  int s = blockIdx.x * 32 + sl;
  if (s < NN) {
    int d = deg[s];
    float a[8] = {0.f, 0.f, 0.f, 0.f, 0.f, 0.f, 0.f, 0.f};
    gather8<32>(he + (long)lane * 4, csr, s * CCAP, s * CCAP + d, a);
    float sc = inv[s];
    float4 o0 = {a[0] * sc, a[1] * sc, a[2] * sc, a[3] * sc};
    float4 o1 = {a[4] * sc, a[5] * sc, a[6] * sc, a[7] * sc};
    *(float4*)(&rows[sl * R64 + lane * 8]) = o0;
    *(float4*)(&rows[sl * R64 + lane * 8 + 4]) = o1;
  }
  __syncthreads();
#pragma unroll
  for (int pass = 0; pass < 2; ++pass) {
    int rl = pass * 16 + (threadIdx.x >> 4);
    int r = blockIdx.x * 32 + rl;
    int l = (threadIdx.x & 15) * 4;
    float vx = b2[l + 0], vy = b2[l + 1], vz = b2[l + 2], vw = b2[l + 3];
    const float* row = &rows[rl * R64];
#pragma unroll
    for (int kk = 0; kk < 16; ++kk) {
      float4 rv = *(const float4*)(row + 4 * kk);
      const float* w0 = &Ws[(4 * kk + 0) * 64 + l];
      const float* w1 = &Ws[(4 * kk + 1) * 64 + l];
      const float* w2 = &Ws[(4 * kk + 2) * 64 + l];
      const float* w3 = &Ws[(4 * kk + 3) * 64 + l];
      vx += rv.x * w0[0] + rv.y * w1[0] + rv.z * w2[0] + rv.w * w3[0];
      vy += rv.x * w0[1] + rv.y * w1[1] + rv.z * w2[1] + rv.w * w3[1];
      vz += rv.x * w0[2] + rv.y * w1[2] + rv.z * w2[2] + rv.w * w3[2];
      vw += rv.x * w0[3] + rv.y * w1[3] + rv.z * w2[3] + rv.w * w3[3];
    }
    if (r < NN) {
      vx = vx >= 0.f ? vx : 0.01f * vx;
      vy = vy >= 0.f ? vy : 0.01f * vy;
      vz = vz >= 0.f ? vz : 0.01f * vz;
      vw = vw >= 0.f ? vw : 0.01f * vw;
      uint2 o = {pack2(vx, vy), pack2(vz, vw)};
      *(uint2*)(h2 + (long)r * 32 + (l >> 1)) = o;
    }
  }
}

// logvar head: lv[r,:] = a3@Wlv + blv   (fp32 in/out, 16 KB LDS)
__global__ __launch_bounds__(256) void k_gemm_lv(const float* __restrict__ a3,
                                                 const float* __restrict__ Wlv,
                                                 const float* __restrict__ blv,
                                                 float* __restrict__ lv) {
  __shared__ float Ws[64 * 64];
  for (int i = threadIdx.x; i < 64 * 64; i += 256) Ws[i] = Wlv[i];
  __syncthreads();
  int g = blockIdx.x * 256 + threadIdx.x;
  int r = g >> 4;
  int l = (g & 15) * 4;
  if (r >= NN) return;
  const float4* rowv = (const float4*)(a3 + (long)r * 64);
  float vx = blv[l + 0], vy = blv[l + 1], vz = blv[l + 2], vw = blv[l + 3];
#pragma unroll
  for (int kk = 0; kk < 16; ++kk) {
    float4 rv = rowv[kk];
    const float* w0 = &Ws[(4 * kk + 0) * 64 + l];
    const float* w1 = &Ws[(4 * kk + 1) * 64 + l];
    const float* w2 = &Ws[(4 * kk + 2) * 64 + l];
    const float* w3 = &Ws[(4 * kk + 3) * 64 + l];
    vx += rv.x * w0[0] + rv.y * w1[0] + rv.z * w2[0] + rv.w * w3[0];
    vy += rv.x * w0[1] + rv.y * w1[1] + rv.z * w2[1] + rv.w * w3[1];
    vz += rv.x * w0[2] + rv.y * w1[2] + rv.z * w2[2] + rv.w * w3[2];
    vw += rv.x * w0[3] + rv.y * w1[3] + rv.z * w2[3] + rv.w * w3[3];
  }
  float4 o = {vx, vy, vz, vw};
  *(float4*)(&lv[(long)r * 64 + l]) = o;
}

// decode from a3 via composed C1/c1; one thread per row; norm accumulate.
__global__ __launch_bounds__(256) void k_decode(
    const float* __restrict__ a3, const float* __restrict__ C1,
    const float* __restrict__ c1, const float* __restrict__ dW2,
    const float* __restrict__ db2, const float* __restrict__ dW3,
    const float* __restrict__ db3, float* __restrict__ out,
    float* __restrict__ norm_acc) {
  __shared__ float C1s[64 * 32];
  __shared__ float W2s[32 * 8];
  __shared__ float W3s[8];
  __shared__ float c1s[32];
  __shared__ float b2s[8];
  __shared__ float b3s;
  for (int i = threadIdx.x; i < 2048; i += 256) C1s[i] = C1[i];
  if (threadIdx.x < 256) W2s[threadIdx.x] = dW2[threadIdx.x];
  if (threadIdx.x < 32) c1s[threadIdx.x] = c1[threadIdx.x];
  if (threadIdx.x < 8) {
    W3s[threadIdx.x] = dW3[threadIdx.x];
    b2s[threadIdx.x] = db2[threadIdx.x];
  }
  if (threadIdx.x == 0) b3s = db3[0];
  __syncthreads();
  int n = blockIdx.x * 256 + threadIdx.x;
  float dval = 0.0f;
  if (n < NN) {
    float acc[32];
#pragma unroll
    for (int j = 0; j < 32; ++j) acc[j] = c1s[j];
    const float4* rowv = (const float4*)(a3 + (long)n * 64);
    for (int kk = 0; kk < 16; ++kk) {
      float4 rv = rowv[kk];
      const float* r0 = &C1s[(4 * kk + 0) * 32];
      const float* r1 = &C1s[(4 * kk + 1) * 32];
      const float* r2 = &C1s[(4 * kk + 2) * 32];
      const float* r3 = &C1s[(4 * kk + 3) * 32];
#pragma unroll
      for (int j = 0; j < 32; ++j)
        acc[j] += rv.x * r0[j] + rv.y * r1[j] + rv.z * r2[j] + rv.w * r3[j];
    }
    float a2[8];
#pragma unroll
    for (int j = 0; j < 8; ++j) a2[j] = b2s[j];
#pragma unroll
    for (int k = 0; k < 32; ++k) {
      float v = acc[k];
      v = v >= 0.f ? v : 0.01f * v;
#pragma unroll
      for (int j = 0; j < 8; ++j) a2[j] += v * W2s[k * 8 + j];
    }
    float s = b3s;
#pragma unroll
    for (int k = 0; k < 8; ++k) {
      float v = a2[k];
      v = v >= 0.f ? v : 0.01f * v;
      s += v * W3s[k];
    }
    dval = s;
    out[n] = dval;        // z_orth (unscaled)
    out[NN + n] = dval;   // mu_orth (z == mu in eval mode)
  }
  __shared__ float red[256];
  red[threadIdx.x] = dval * dval;
  __syncthreads();
  for (int off = 128; off > 0; off >>= 1) {
    if (threadIdx.x < off) red[threadIdx.x] += red[threadIdx.x + off];
    __syncthreads();
  }
  if (threadIdx.x == 0) atomicAdd(norm_acc, red[0]);
}

__global__ __launch_bounds__(256) void k_scale(float* __restrict__ out,
                                               const float* __restrict__ norm_acc) {
  int i = blockIdx.x * 256 + threadIdx.x;
  if (i < 2 * NN) {
    float nrm = sqrtf(*norm_acc);
    float sc = 1.0f / fmaxf(nrm, 1e-8f);
    out[i] *= sc;
  }
}

extern "C" void kernel_launch(void* const* d_in, const int* in_sizes, int n_in,
                              void* d_out, int out_size, void* d_ws, size_t ws_size,
                              hipStream_t stream) {
  const float* x   = (const float*)d_in[0];
  const int*   hei = (const int*)d_in[1];  // [2, NP]
  const int* nidx = hei;
  const int* eidx = hei + NP;
  const float* W1  = (const float*)d_in[2];
  const float* b1  = (const float*)d_in[3];
  const float* g1  = (const float*)d_in[4];
  const float* be1 = (const float*)d_in[5];
  const float* W2  = (const float*)d_in[6];
  const float* b2  = (const float*)d_in[7];
  const float* Wmu = (const float*)d_in[8];
  const float* bmu = (const float*)d_in[9];
  const float* Wlv = (const float*)d_in[10];
  const float* blv = (const float*)d_in[11];
  const float* dW1 = (const float*)d_in[12];
  const float* db1 = (const float*)d_in[13];
  const float* dW2 = (const float*)d_in[14];
  const float* db2 = (const float*)d_in[15];
  const float* dW3 = (const float*)d_in[16];
  const float* db3 = (const float*)d_in[17];
  float* out = (float*)d_out;

  int*    wi = (int*)d_ws;
  float*  wf = (float*)d_ws;
  uint32* wu = (uint32*)d_ws;

  // zero gcurE/gcurN/norm (words 0 .. 1087)
  hipMemsetAsync(d_ws, 0, (size_t)1088 * 4, stream);

  // front: bucketize + compose + cast in one launch
  k_front<<<NBK + 1 + CASTB, 256, 0, stream>>>(nidx, eidx,
                                               wi + O_GCURE, wi + O_GCURN,
                                               wi + O_BKTE, wi + O_BKTN,
                                               Wmu, bmu, dW1, db1,
                                               wf + O_C1, wf + O_C1B,
                                               x, wu + O_XB);
  k_csr2<<<2 * NBK, 256, 0, stream>>>(wi + O_GCURE, wi + O_GCURN,
                                      wi + O_BKTE, wi + O_BKTN,
                                      wi + O_CSRE, wi + O_CSRN,
                                      wi + O_DEGE, wi + O_DEGN,
                                      wf + O_BINV, wf + O_DINV);

  const int G32 = (NE * 4 + 255) / 256;   // edge agg 32-wide
  const int G64 = (NE * 8 + 255) / 256;   // edge agg 64-wide
  const int GG  = NN * 16 / 256;          // row kernels, 16 lanes/row

  // layer 1
  k_seg_agg<32, false><<<G32, 256, 0, stream>>>(wu + O_XB, wi + O_CSRE,
                                                wi + O_DEGE, wf + O_BINV,
                                                wu + O_HE, nullptr);
  k_agg_ln<<<(NN + 63) / 64, 256, 0, stream>>>(wu + O_HE, wi + O_CSRN,
                                               wi + O_DEGN, wf + O_DINV,
                                               W1, b1, g1, be1, wu + O_T);
  // layer 2
  k_seg_agg<64, false><<<G64, 256, 0, stream>>>(wu + O_T, wi + O_CSRE,
                                                wi + O_DEGE, wf + O_BINV,
                                                wu + O_HE, nullptr);
  k_agg_lk<<<(NN + 31) / 32, 256, 0, stream>>>(wu + O_HE, wi + O_CSRN,
                                               wi + O_DEGN, wf + O_DINV,
                                               W2, b2, wu + O_T);
  // heads: split path (R10-proven) — agg -> a3 -> lv GEMM + decode
  k_seg_agg<64, false><<<G64, 256, 0, stream>>>(wu + O_T, wi + O_CSRE,
                                                wi + O_DEGE, wf + O_BINV,
                                                wu + O_HE, nullptr);
  k_seg_agg<64, true><<<G64, 256, 0, stream>>>(wu + O_HE, wi + O_CSRN,
                                               wi + O_DEGN, wf + O_DINV,
                                               nullptr, wf + O_A);
  k_gemm_lv<<<GG, 256, 0, stream>>>(wf + O_A, Wlv, blv, out + 2 * NN);
  k_decode<<<(NN + 255) / 256, 256, 0, stream>>>(wf + O_A, wf + O_C1, wf + O_C1B,
                                                 dW2, db2, dW3, db3,
                                                 out, wf + O_NORM);
  k_scale<<<(2 * NN + 255) / 256, 256, 0, stream>>>(out, wf + O_NORM);
}

// Round 13
// 391.210 us; speedup vs baseline: 1.1107x; 1.0345x over previous
//
#include <hip/hip_runtime.h>

// HypergraphModel on MI355X.
// R13: apply the validated fusion pattern (R12: k_agg_lk = gather + thin
//      full-width consumer, 25.6 KB LDS, no serial tail) to the heads path:
//      k_agg_lv = node-gather + lv GEMM (phase 2, all threads) + bf16 a3
//      side-write for k_decode. Replaces seg_agg<64,F32> + k_gemm_lv
//      (102 MB traffic -> 51 MB, one launch fewer). k_decode reads bf16 a3.
//      Everything else = R12 (proven).

#define NN 100000
#define NE 100000
#define NP 1600000
#define NBK  391   // buckets per side (256 ids each); NBK*256 = 100,096
#define BCAP 4608  // bucket cap (mean 4096, +8 sigma)
#define CCAP 48    // padded CSR row stride (Poisson(16) + >8 sigma)

// ws offsets in 4-byte words (sizes in words) — non-overlapping:
#define O_GCURE 0              // 512  (zeroed)
#define O_GCURN 512            // 512  (zeroed)
#define O_NORM  1024           // 64   (zeroed)
#define O_DEGE  1088           // 100,000
#define O_DEGN  101088         // 100,000
#define O_BINV  201088         // 100,000
#define O_DINV  301088         // 100,000
#define O_BKTE  401088         // NBK*BCAP = 1,801,728
#define O_BKTN  2202816        // 1,801,728
#define O_CSRE  4004544        // NE*CCAP = 4,800,000
#define O_CSRN  8804544        // 4,800,000
#define O_XB    13604544       // bf16 100000x32 = 1,600,000 words
#define O_T     15204544       // bf16 100000x64 = 3,200,000 words
#define O_HE    18404544       // bf16 100000x64 = 3,200,000 words
#define O_C1    21604544       // fp32 64x32 = 2,048
#define O_C1B   21606592       // fp32 32
#define O_A     21606624       // bf16 100000x64 = 1,600,000 words
// end 23,206,624 words = 92.8 MB

typedef unsigned int uint32;

__device__ __forceinline__ float b2f_lo(uint32 u) { return __uint_as_float(u << 16); }
__device__ __forceinline__ float b2f_hi(uint32 u) { return __uint_as_float(u & 0xFFFF0000u); }
__device__ __forceinline__ uint32 f2b(float f) {  // RNE fp32 -> bf16
  uint32 b = __float_as_uint(f);
  return (b + 0x7FFFu + ((b >> 16) & 1u)) >> 16;
}
__device__ __forceinline__ uint32 pack2(float lo, float hi) {
  return f2b(lo) | (f2b(hi) << 16);
}

// 8-elem gather-accumulate over a padded-CSR segment (bf16 rows, ROWU uints
// per row, 16B per lane). a[0..7] must be zeroed by caller.
template <int ROWU>
__device__ __forceinline__ void gather8(const uint32* __restrict__ base,
                                        const int* __restrict__ csr,
                                        int beg, int end, float* a) {
#define ACC(q)                                        \
  a[0] += b2f_lo(q.x); a[1] += b2f_hi(q.x);           \
  a[2] += b2f_lo(q.y); a[3] += b2f_hi(q.y);           \
  a[4] += b2f_lo(q.z); a[5] += b2f_hi(q.z);           \
  a[6] += b2f_lo(q.w); a[7] += b2f_hi(q.w);
  int p = beg;
  for (; p + 8 <= end; p += 8) {
    int4 i4a = *(const int4*)(csr + p);
    int4 i4b = *(const int4*)(csr + p + 4);
    uint4 q0 = *(const uint4*)(base + (long)i4a.x * ROWU);
    uint4 q1 = *(const uint4*)(base + (long)i4a.y * ROWU);
    uint4 q2 = *(const uint4*)(base + (long)i4a.z * ROWU);
    uint4 q3 = *(const uint4*)(base + (long)i4a.w * ROWU);
    uint4 q4 = *(const uint4*)(base + (long)i4b.x * ROWU);
    uint4 q5 = *(const uint4*)(base + (long)i4b.y * ROWU);
    uint4 q6 = *(const uint4*)(base + (long)i4b.z * ROWU);
    uint4 q7 = *(const uint4*)(base + (long)i4b.w * ROWU);
    ACC(q0) ACC(q1) ACC(q2) ACC(q3) ACC(q4) ACC(q5) ACC(q6) ACC(q7)
  }
  for (; p + 4 <= end; p += 4) {
    int4 i4 = *(const int4*)(csr + p);
    uint4 q0 = *(const uint4*)(base + (long)i4.x * ROWU);
    uint4 q1 = *(const uint4*)(base + (long)i4.y * ROWU);
    uint4 q2 = *(const uint4*)(base + (long)i4.z * ROWU);
    uint4 q3 = *(const uint4*)(base + (long)i4.w * ROWU);
    ACC(q0) ACC(q1) ACC(q2) ACC(q3)
  }
  for (; p < end; ++p) {
    uint4 q = *(const uint4*)(base + (long)csr[p] * ROWU);
    ACC(q)
  }
#undef ACC
}

// ---- k_front: bucketize (blocks 0..NBK-1) + compose (block NBK) +
//      cast x->bf16 (blocks NBK+1 ..). All independent.
#define CASTB ((NN * 32 / 8 + 255) / 256)  // 1563
__global__ __launch_bounds__(256) void k_front(const int* __restrict__ nidx,
                                               const int* __restrict__ eidx,
                                               int* __restrict__ gcurE,
                                               int* __restrict__ gcurN,
                                               int* __restrict__ bktE,
                                               int* __restrict__ bktN,
                                               const float* __restrict__ Wmu,
                                               const float* __restrict__ bmu,
                                               const float* __restrict__ dW1,
                                               const float* __restrict__ db1,
                                               float* __restrict__ C1,
                                               float* __restrict__ c1,
                                               const float* __restrict__ x,
                                               uint32* __restrict__ xb) {
  __shared__ int cntE[NBK], cntN[NBK], curE[NBK], curN[NBK];
  if (blockIdx.x < NBK) {
    for (int i = threadIdx.x; i < NBK; i += 256) { cntE[i] = 0; cntN[i] = 0; }
    __syncthreads();
    int base = blockIdx.x * 4096 + threadIdx.x * 16;
    int n[16], e[16];
    int cnt = 0;
    if (base + 16 <= NP) {
#pragma unroll
      for (int q = 0; q < 4; ++q) {
        int4 a = *(const int4*)(nidx + base + 4 * q);
        int4 b = *(const int4*)(eidx + base + 4 * q);
        n[4 * q + 0] = a.x; n[4 * q + 1] = a.y; n[4 * q + 2] = a.z; n[4 * q + 3] = a.w;
        e[4 * q + 0] = b.x; e[4 * q + 1] = b.y; e[4 * q + 2] = b.z; e[4 * q + 3] = b.w;
      }
      cnt = 16;
    } else {
      for (int i = 0; i < 16 && base + i < NP; ++i) {
        n[i] = nidx[base + i];
        e[i] = eidx[base + i];
        ++cnt;
      }
    }
    for (int i = 0; i < cnt; ++i) {
      atomicAdd(&cntE[e[i] >> 8], 1);
      atomicAdd(&cntN[n[i] >> 8], 1);
    }
    __syncthreads();
    for (int i = threadIdx.x; i < NBK; i += 256) {
      curE[i] = atomicAdd(&gcurE[i], cntE[i]);
      curN[i] = atomicAdd(&gcurN[i], cntN[i]);
    }
    __syncthreads();
    for (int i = 0; i < cnt; ++i) {
      int be = e[i] >> 8, bn = n[i] >> 8;
      int se = atomicAdd(&curE[be], 1);
      if (se < BCAP) bktE[be * BCAP + se] = ((e[i] & 255) << 24) | n[i];
      int sn = atomicAdd(&curN[bn], 1);
      if (sn < BCAP) bktN[bn * BCAP + sn] = ((n[i] & 255) << 24) | e[i];
    }
  } else if (blockIdx.x == NBK) {
    int t = threadIdx.x;
    for (int idx = t; idx < 64 * 32; idx += 256) {
      int i = idx >> 5, j = idx & 31;
      float s = 0.f;
      for (int k = 0; k < 64; ++k) s += Wmu[i * 64 + k] * dW1[k * 32 + j];
      C1[idx] = s;
    }
    if (t < 32) {
      float s = db1[t];
      for (int k = 0; k < 64; ++k) s += bmu[k] * dW1[k * 32 + t];
      c1[t] = s;
    }
  } else {
    int t = (blockIdx.x - NBK - 1) * 256 + threadIdx.x;
    if (t < NN * 32 / 8) {
      const float4 f0 = *(const float4*)(x + (long)t * 8);
      const float4 f1 = *(const float4*)(x + (long)t * 8 + 4);
      uint4 o;
      o.x = pack2(f0.x, f0.y);
      o.y = pack2(f0.z, f0.w);
      o.z = pack2(f1.x, f1.y);
      o.w = pack2(f1.z, f1.w);
      *(uint4*)(xb + (long)t * 4) = o;
    }
  }
}

// ---- Pass B: per-bucket padded-CSR build + deg + 1/deg (LDS atomics only).
__global__ __launch_bounds__(256) void k_csr2(const int* __restrict__ gcurE,
                                              const int* __restrict__ gcurN,
                                              const int* __restrict__ bktE,
                                              const int* __restrict__ bktN,
                                              int* __restrict__ csrE,
                                              int* __restrict__ csrN,
                                              int* __restrict__ degE,
                                              int* __restrict__ degN,
                                              float* __restrict__ invE,
                                              float* __restrict__ invN) {
  int bb = blockIdx.x;
  bool es = bb < NBK;
  int b = es ? bb : bb - NBK;
  const int* gcur = es ? gcurE : gcurN;
  const int* bkt  = es ? bktE : bktN;
  int*   csr = es ? csrE : csrN;
  int*   deg = es ? degE : degN;
  float* inv = es ? invE : invN;

  __shared__ int ent[BCAP];
  __shared__ int cnt[256], cur[256];
  int m = gcur[b];
  if (m > BCAP) m = BCAP;
  for (int i = threadIdx.x; i < m; i += 256) ent[i] = bkt[b * BCAP + i];
  cnt[threadIdx.x] = 0;
  __syncthreads();
  for (int i = threadIdx.x; i < m; i += 256)
    atomicAdd(&cnt[((unsigned)ent[i]) >> 24], 1);
  __syncthreads();
  int id = (b << 8) + threadIdx.x;
  if (id < NN) {  // NN == NE
    int d = cnt[threadIdx.x];
    deg[id] = d < CCAP ? d : CCAP;
    inv[id] = d > 0 ? 1.0f / (float)d : 0.0f;
  }
  cur[threadIdx.x] = 0;
  __syncthreads();
  for (int i = threadIdx.x; i < m; i += 256) {
    unsigned v = (unsigned)ent[i];
    int loc = v >> 24;
    int payload = v & 0xFFFFFF;
    int slot = atomicAdd(&cur[loc], 1);
    if (slot < CCAP) csr[(long)((b << 8) + loc) * CCAP + slot] = payload;
  }
}

// Edge-side gather-reduce, bf16 in / bf16 out.
template <int W>
__global__ __launch_bounds__(256) void k_seg_agg(const uint32* __restrict__ tb,
                                                 const int* __restrict__ csr,
                                                 const int* __restrict__ deg,
                                                 const float* __restrict__ inv,
                                                 uint32* __restrict__ dstb) {
  constexpr int LANES = W / 8;
  constexpr int ROWU = W / 2;
  int g = blockIdx.x * 256 + threadIdx.x;
  int s = g / LANES;
  int lane = g % LANES;
  if (s >= NE) return;
  int d = deg[s];
  float a[8] = {0.f, 0.f, 0.f, 0.f, 0.f, 0.f, 0.f, 0.f};
  gather8<ROWU>(tb + (long)lane * 4, csr, s * CCAP, s * CCAP + d, a);
  float sc = inv[s];
  uint4 o;
  o.x = pack2(a[0] * sc, a[1] * sc);
  o.y = pack2(a[2] * sc, a[3] * sc);
  o.z = pack2(a[4] * sc, a[5] * sc);
  o.w = pack2(a[6] * sc, a[7] * sc);
  *(uint4*)(dstb + (long)s * ROWU + lane * 4) = o;
}

// ---- Fused node-agg (32-wide) + GEMM(32->64) + LN + leaky -> bf16 t.
#define R32 40
__global__ __launch_bounds__(256) void k_agg_ln(
    const uint32* __restrict__ he, const int* __restrict__ csr,
    const int* __restrict__ deg, const float* __restrict__ inv,
    const float* __restrict__ W1, const float* __restrict__ b1,
    const float* __restrict__ g1, const float* __restrict__ be1,
    uint32* __restrict__ h) {
  __shared__ float Ws[32 * 64];
  __shared__ __align__(16) float rows[64 * R32];
  for (int i = threadIdx.x; i < 32 * 64; i += 256) Ws[i] = W1[i];
  int sl = threadIdx.x >> 2;
  int lane = threadIdx.x & 3;
  int s = blockIdx.x * 64 + sl;
  if (s < NN) {
    int d = deg[s];
    float a[8] = {0.f, 0.f, 0.f, 0.f, 0.f, 0.f, 0.f, 0.f};
    gather8<16>(he + (long)lane * 4, csr, s * CCAP, s * CCAP + d, a);
    float sc = inv[s];
    float4 o0 = {a[0] * sc, a[1] * sc, a[2] * sc, a[3] * sc};
    float4 o1 = {a[4] * sc, a[5] * sc, a[6] * sc, a[7] * sc};
    *(float4*)(&rows[sl * R32 + lane * 8]) = o0;
    *(float4*)(&rows[sl * R32 + lane * 8 + 4]) = o1;
  }
  __syncthreads();
#pragma unroll
  for (int pass = 0; pass < 4; ++pass) {
    int rl = pass * 16 + (threadIdx.x >> 4);
    int r = blockIdx.x * 64 + rl;
    int l = (threadIdx.x & 15) * 4;
    float vx = b1[l + 0], vy = b1[l + 1], vz = b1[l + 2], vw = b1[l + 3];
    const float* row = &rows[rl * R32];
#pragma unroll
    for (int kk = 0; kk < 8; ++kk) {
      float4 rv = *(const float4*)(row + 4 * kk);
      const float* w0 = &Ws[(4 * kk + 0) * 64 + l];
      const float* w1 = &Ws[(4 * kk + 1) * 64 + l];
      const float* w2 = &Ws[(4 * kk + 2) * 64 + l];
      const float* w3 = &Ws[(4 * kk + 3) * 64 + l];
      vx += rv.x * w0[0] + rv.y * w1[0] + rv.z * w2[0] + rv.w * w3[0];
      vy += rv.x * w0[1] + rv.y * w1[1] + rv.z * w2[1] + rv.w * w3[1];
      vz += rv.x * w0[2] + rv.y * w1[2] + rv.z * w2[2] + rv.w * w3[2];
      vw += rv.x * w0[3] + rv.y * w1[3] + rv.z * w2[3] + rv.w * w3[3];
    }
    float sm = vx + vy + vz + vw;
    float s2 = vx * vx + vy * vy + vz * vz + vw * vw;
    for (int m = 1; m <= 8; m <<= 1) {
      sm += __shfl_xor(sm, m, 64);
      s2 += __shfl_xor(s2, m, 64);
    }
    float mean = sm * (1.0f / 64.0f);
    float var = s2 * (1.0f / 64.0f) - mean * mean;
    float rstd = rsqrtf(var + 1e-5f);
    if (r < NN) {
      float ox = (vx - mean) * rstd * g1[l + 0] + be1[l + 0];
      float oy = (vy - mean) * rstd * g1[l + 1] + be1[l + 1];
      float oz = (vz - mean) * rstd * g1[l + 2] + be1[l + 2];
      float ow = (vw - mean) * rstd * g1[l + 3] + be1[l + 3];
      ox = ox >= 0.f ? ox : 0.01f * ox;
      oy = oy >= 0.f ? oy : 0.01f * oy;
      oz = oz >= 0.f ? oz : 0.01f * oz;
      ow = ow >= 0.f ? ow : 0.01f * ow;
      uint2 o = {pack2(ox, oy), pack2(oz, ow)};
      *(uint2*)(h + (long)r * 32 + (l >> 1)) = o;
    }
  }
}

// ---- Fused node-agg (64-wide) + GEMM(64->64) + leaky -> bf16 t.
#define R64 72
__global__ __launch_bounds__(256) void k_agg_lk(
    const uint32* __restrict__ he, const int* __restrict__ csr,
    const int* __restrict__ deg, const float* __restrict__ inv,
    const float* __restrict__ W2, const float* __restrict__ b2,
    uint32* __restrict__ h2) {
  __shared__ float Ws[64 * 64];
  __shared__ __align__(16) float rows[32 * R64];
  for (int i = threadIdx.x; i < 64 * 64; i += 256) Ws[i] = W2[i];
  int sl = threadIdx.x >> 3;
  int lane = threadIdx.x & 7;
  int s = blockIdx.x * 32 + sl;
  if (s < NN) {
    int d = deg[s];
    float a[8] = {0.f, 0.f, 0.f, 0.f, 0.f, 0.f, 0.f, 0.f};
    gather8<32>(he + (long)lane * 4, csr, s * CCAP, s * CCAP + d, a);
    float sc = inv[s];
    float4 o0 = {a[0] * sc, a[1] * sc, a[2] * sc, a[3] * sc};
    float4 o1 = {a[4] * sc, a[5] * sc, a[6] * sc, a[7] * sc};
    *(float4*)(&rows[sl * R64 + lane * 8]) = o0;
    *(float4*)(&rows[sl * R64 + lane * 8 + 4]) = o1;
  }
  __syncthreads();
#pragma unroll
  for (int pass = 0; pass < 2; ++pass) {
    int rl = pass * 16 + (threadIdx.x >> 4);
    int r = blockIdx.x * 32 + rl;
    int l = (threadIdx.x & 15) * 4;
    float vx = b2[l + 0], vy = b2[l + 1], vz = b2[l + 2], vw = b2[l + 3];
    const float* row = &rows[rl * R64];
#pragma unroll
    for (int kk = 0; kk < 16; ++kk) {
      float4 rv = *(const float4*)(row + 4 * kk);
      const float* w0 = &Ws[(4 * kk + 0) * 64 + l];
      const float* w1 = &Ws[(4 * kk + 1) * 64 + l];
      const float* w2 = &Ws[(4 * kk + 2) * 64 + l];
      const float* w3 = &Ws[(4 * kk + 3) * 64 + l];
      vx += rv.x * w0[0] + rv.y * w1[0] + rv.z * w2[0] + rv.w * w3[0];
      vy += rv.x * w0[1] + rv.y * w1[1] + rv.z * w2[1] + rv.w * w3[1];
      vz += rv.x * w0[2] + rv.y * w1[2] + rv.z * w2[2] + rv.w * w3[2];
      vw += rv.x * w0[3] + rv.y * w1[3] + rv.z * w2[3] + rv.w * w3[3];
    }
    if (r < NN) {
      vx = vx >= 0.f ? vx : 0.01f * vx;
      vy = vy >= 0.f ? vy : 0.01f * vy;
      vz = vz >= 0.f ? vz : 0.01f * vz;
      vw = vw >= 0.f ? vw : 0.01f * vw;
      uint2 o = {pack2(vx, vy), pack2(vz, vw)};
      *(uint2*)(h2 + (long)r * 32 + (l >> 1)) = o;
    }
  }
}

// ---- Fused node-agg (64-wide) + logvar GEMM; also emits bf16 a3 for decode.
// Mirror of k_agg_lk (proven 25.6 KB LDS shape, no serial tail).
__global__ __launch_bounds__(256) void k_agg_lv(
    const uint32* __restrict__ he, const int* __restrict__ csr,
    const int* __restrict__ deg, const float* __restrict__ inv,
    const float* __restrict__ Wlv, const float* __restrict__ blv,
    uint32* __restrict__ a3b, float* __restrict__ lv) {
  __shared__ float Ws[64 * 64];
  __shared__ __align__(16) float rows[32 * R64];
  for (int i = threadIdx.x; i < 64 * 64; i += 256) Ws[i] = Wlv[i];
  int sl = threadIdx.x >> 3;
  int lane = threadIdx.x & 7;
  int s = blockIdx.x * 32 + sl;
  if (s < NN) {
    int d = deg[s];
    float a[8] = {0.f, 0.f, 0.f, 0.f, 0.f, 0.f, 0.f, 0.f};
    gather8<32>(he + (long)lane * 4, csr, s * CCAP, s * CCAP + d, a);
    float sc = inv[s];
    float4 o0 = {a[0] * sc, a[1] * sc, a[2] * sc, a[3] * sc};
    float4 o1 = {a[4] * sc, a[5] * sc, a[6] * sc, a[7] * sc};
    *(float4*)(&rows[sl * R64 + lane * 8]) = o0;
    *(float4*)(&rows[sl * R64 + lane * 8 + 4]) = o1;
    // bf16 a3 side-write for k_decode (uint4 = 8 bf16 per lane)
    uint4 ob;
    ob.x = pack2(o0.x, o0.y);
    ob.y = pack2(o0.z, o0.w);
    ob.z = pack2(o1.x, o1.y);
    ob.w = pack2(o1.z, o1.w);
    *(uint4*)(a3b + (long)s * 32 + lane * 4) = ob;
  }
  __syncthreads();
#pragma unroll
  for (int pass = 0; pass < 2; ++pass) {
    int rl = pass * 16 + (threadIdx.x >> 4);
    int r = blockIdx.x * 32 + rl;
    int l = (threadIdx.x & 15) * 4;
    float vx = blv[l + 0], vy = blv[l + 1], vz = blv[l + 2], vw = blv[l + 3];
    const float* row = &rows[rl * R64];
#pragma unroll
    for (int kk = 0; kk < 16; ++kk) {
      float4 rv = *(const float4*)(row + 4 * kk);
      const float* w0 = &Ws[(4 * kk + 0) * 64 + l];
      const float* w1 = &Ws[(4 * kk + 1) * 64 + l];
      const float* w2 = &Ws[(4 * kk + 2) * 64 + l];
      const float* w3 = &Ws[(4 * kk + 3) * 64 + l];
      vx += rv.x * w0[0] + rv.y * w1[0] + rv.z * w2[0] + rv.w * w3[0];
      vy += rv.x * w0[1] + rv.y * w1[1] + rv.z * w2[1] + rv.w * w3[1];
      vz += rv.x * w0[2] + rv.y * w1[2] + rv.z * w2[2] + rv.w * w3[2];
      vw += rv.x * w0[3] + rv.y * w1[3] + rv.z * w2[3] + rv.w * w3[3];
    }
    if (r < NN) {
      float4 o = {vx, vy, vz, vw};
      *(float4*)(&lv[(long)r * 64 + l]) = o;
    }
  }
}

// decode from bf16 a3 via composed C1/c1; one thread per row; norm accumulate.
__global__ __launch_bounds__(256) void k_decode(
    const uint32* __restrict__ a3b, const float* __restrict__ C1,
    const float* __restrict__ c1, const float* __restrict__ dW2,
    const float* __restrict__ db2, const float* __restrict__ dW3,
    const float* __restrict__ db3, float* __restrict__ out,
    float* __restrict__ norm_acc) {
  __shared__ float C1s[64 * 32];
  __shared__ float W2s[32 * 8];
  __shared__ float W3s[8];
  __shared__ float c1s[32];
  __shared__ float b2s[8];
  __shared__ float b3s;
  for (int i = threadIdx.x; i < 2048; i += 256) C1s[i] = C1[i];
  if (threadIdx.x < 256) W2s[threadIdx.x] = dW2[threadIdx.x];
  if (threadIdx.x < 32) c1s[threadIdx.x] = c1[threadIdx.x];
  if (threadIdx.x < 8) {
    W3s[threadIdx.x] = dW3[threadIdx.x];
    b2s[threadIdx.x] = db2[threadIdx.x];
  }
  if (threadIdx.x == 0) b3s = db3[0];
  __syncthreads();
  int n = blockIdx.x * 256 + threadIdx.x;
  float dval = 0.0f;
  if (n < NN) {
    float acc[32];
#pragma unroll
    for (int j = 0; j < 32; ++j) acc[j] = c1s[j];
    const uint32* rowb = a3b + (long)n * 32;
    for (int kk = 0; kk < 8; ++kk) {
      uint4 q = *(const uint4*)(rowb + kk * 4);
      float rv0 = b2f_lo(q.x), rv1 = b2f_hi(q.x);
      float rv2 = b2f_lo(q.y), rv3 = b2f_hi(q.y);
      float rv4 = b2f_lo(q.z), rv5 = b2f_hi(q.z);
      float rv6 = b2f_lo(q.w), rv7 = b2f_hi(q.w);
      const float* r0 = &C1s[(8 * kk + 0) * 32];
      const float* r1 = &C1s[(8 * kk + 1) * 32];
      const float* r2 = &C1s[(8 * kk + 2) * 32];
      const float* r3 = &C1s[(8 * kk + 3) * 32];
      const float* r4 = &C1s[(8 * kk + 4) * 32];
      const float* r5 = &C1s[(8 * kk + 5) * 32];
      const float* r6 = &C1s[(8 * kk + 6) * 32];
      const float* r7 = &C1s[(8 * kk + 7) * 32];
#pragma unroll
      for (int j = 0; j < 32; ++j)
        acc[j] += rv0 * r0[j] + rv1 * r1[j] + rv2 * r2[j] + rv3 * r3[j] +
                  rv4 * r4[j] + rv5 * r5[j] + rv6 * r6[j] + rv7 * r7[j];
    }
    float a2[8];
#pragma unroll
    for (int j = 0; j < 8; ++j) a2[j] = b2s[j];
#pragma unroll
    for (int k = 0; k < 32; ++k) {
      float v = acc[k];
      v = v >= 0.f ? v : 0.01f * v;
#pragma unroll
      for (int j = 0; j < 8; ++j) a2[j] += v * W2s[k * 8 + j];
    }
    float s = b3s;
#pragma unroll
    for (int k = 0; k < 8; ++k) {
      float v = a2[k];
      v = v >= 0.f ? v : 0.01f * v;
      s += v * W3s[k];
    }
    dval = s;
    out[n] = dval;        // z_orth (unscaled)
    out[NN + n] = dval;   // mu_orth (z == mu in eval mode)
  }
  __shared__ float red[256];
  red[threadIdx.x] = dval * dval;
  __syncthreads();
  for (int off = 128; off > 0; off >>= 1) {
    if (threadIdx.x < off) red[threadIdx.x] += red[threadIdx.x + off];
    __syncthreads();
  }
  if (threadIdx.x == 0) atomicAdd(norm_acc, red[0]);
}

__global__ __launch_bounds__(256) void k_scale(float* __restrict__ out,
                                               const float* __restrict__ norm_acc) {
  int i = blockIdx.x * 256 + threadIdx.x;
  if (i < 2 * NN) {
    float nrm = sqrtf(*norm_acc);
    float sc = 1.0f / fmaxf(nrm, 1e-8f);
    out[i] *= sc;
  }
}

extern "C" void kernel_launch(void* const* d_in, const int* in_sizes, int n_in,
                              void* d_out, int out_size, void* d_ws, size_t ws_size,
                              hipStream_t stream) {
  const float* x   = (const float*)d_in[0];
  const int*   hei = (const int*)d_in[1];  // [2, NP]
  const int* nidx = hei;
  const int* eidx = hei + NP;
  const float* W1  = (const float*)d_in[2];
  const float* b1  = (const float*)d_in[3];
  const float* g1  = (const float*)d_in[4];
  const float* be1 = (const float*)d_in[5];
  const float* W2  = (const float*)d_in[6];
  const float* b2  = (const float*)d_in[7];
  const float* Wmu = (const float*)d_in[8];
  const float* bmu = (const float*)d_in[9];
  const float* Wlv = (const float*)d_in[10];
  const float* blv = (const float*)d_in[11];
  const float* dW1 = (const float*)d_in[12];
  const float* db1 = (const float*)d_in[13];
  const float* dW2 = (const float*)d_in[14];
  const float* db2 = (const float*)d_in[15];
  const float* dW3 = (const float*)d_in[16];
  const float* db3 = (const float*)d_in[17];
  float* out = (float*)d_out;

  int*    wi = (int*)d_ws;
  float*  wf = (float*)d_ws;
  uint32* wu = (uint32*)d_ws;

  // zero gcurE/gcurN/norm (words 0 .. 1087)
  hipMemsetAsync(d_ws, 0, (size_t)1088 * 4, stream);

  // front: bucketize + compose + cast in one launch
  k_front<<<NBK + 1 + CASTB, 256, 0, stream>>>(nidx, eidx,
                                               wi + O_GCURE, wi + O_GCURN,
                                               wi + O_BKTE, wi + O_BKTN,
                                               Wmu, bmu, dW1, db1,
                                               wf + O_C1, wf + O_C1B,
                                               x, wu + O_XB);
  k_csr2<<<2 * NBK, 256, 0, stream>>>(wi + O_GCURE, wi + O_GCURN,
                                      wi + O_BKTE, wi + O_BKTN,
                                      wi + O_CSRE, wi + O_CSRN,
                                      wi + O_DEGE, wi + O_DEGN,
                                      wf + O_BINV, wf + O_DINV);

  const int G32 = (NE * 4 + 255) / 256;   // edge agg 32-wide
  const int G64 = (NE * 8 + 255) / 256;   // edge agg 64-wide

  // layer 1
  k_seg_agg<32><<<G32, 256, 0, stream>>>(wu + O_XB, wi + O_CSRE,
                                         wi + O_DEGE, wf + O_BINV, wu + O_HE);
  k_agg_ln<<<(NN + 63) / 64, 256, 0, stream>>>(wu + O_HE, wi + O_CSRN,
                                               wi + O_DEGN, wf + O_DINV,
                                               W1, b1, g1, be1, wu + O_T);
  // layer 2
  k_seg_agg<64><<<G64, 256, 0, stream>>>(wu + O_T, wi + O_CSRE,
                                         wi + O_DEGE, wf + O_BINV, wu + O_HE);
  k_agg_lk<<<(NN + 31) / 32, 256, 0, stream>>>(wu + O_HE, wi + O_CSRN,
                                               wi + O_DEGN, wf + O_DINV,
                                               W2, b2, wu + O_T);
  // heads: fused node-agg + lv GEMM (+ bf16 a3 side-write), then decode
  k_seg_agg<64><<<G64, 256, 0, stream>>>(wu + O_T, wi + O_CSRE,
                                         wi + O_DEGE, wf + O_BINV, wu + O_HE);
  k_agg_lv<<<(NN + 31) / 32, 256, 0, stream>>>(wu + O_HE, wi + O_CSRN,
                                               wi + O_DEGN, wf + O_DINV,
                                               Wlv, blv, wu + O_A, out + 2 * NN);
  k_decode<<<(NN + 255) / 256, 256, 0, stream>>>(wu + O_A, wf + O_C1, wf + O_C1B,
                                                 dW2, db2, dW3, db3,
                                                 out, wf + O_NORM);
  k_scale<<<(2 * NN + 255) / 256, 256, 0, stream>>>(out, wf + O_NORM);
}